// Round 3
// baseline (1673.183 us; speedup 1.0000x reference)
//
#include <hip/hip_runtime.h>
#include <hip/hip_bf16.h>
#include <math.h>

// PhiMoE sparse MoE block. E=8, H=1024, F=2048, T=1024.
// Inputs  (float32): hidden_states [1,1024,1024], gate_w [8,1024],
//   w1 [8,2048,1024], w2 [8,1024,2048], w3 [8,2048,1024]
// Outputs (float32, concat): final [1,1024,1024], router_logits [1024,8]
// Top-2 routing -> gather tokens per expert, 2 grouped GEMMs (f32 loads -> bf16 MFMA).

#define T_TOK 1024
#define H_DIM 1024
#define F_DIM 2048
#define N_EXP 8
#define JIT 0.01f

typedef __bf16 bf16_t;
typedef __bf16 bf16x8 __attribute__((ext_vector_type(8)));
typedef float f32x4 __attribute__((ext_vector_type(4)));
typedef float f32x8v __attribute__((ext_vector_type(8)));

// load 8 contiguous f32 and convert to bf16x8 (for MFMA A/B fragments)
__device__ inline bf16x8 cvt8(const float* __restrict__ p) {
    f32x8v f = *(const f32x8v*)p;
    bf16x8 r;
#pragma unroll
    for (int i = 0; i < 8; i++) r[i] = (bf16_t)f[i];
    return r;
}

// workspace layout (bytes)
#define WS_CNT   0                   // 8 ints
#define WS_BASE  64                  // 8 ints
#define WS_TOK   128                 // 8192 ints  (per-expert token lists, stride T_TOK)
#define WS_WGT   (128 + 32768)       // 8192 floats
#define WS_SLOT  (WS_WGT + 32768)    // 8192 ints
#define WS_INTER 131072              // bf16 [2048][2048] compacted intermediate (8 MB)
#define WS_ACC   (131072 + 8388608)  // f32  [2][1024][1024] slot accumulators (8 MB)

// ---------------- Router: logits + sparsemixer top-2 ----------------
__global__ __launch_bounds__(256) void router_k(
    const float* __restrict__ x, const float* __restrict__ gw,
    float* __restrict__ logits_out,
    int* __restrict__ cnt, int* __restrict__ tok,
    float* __restrict__ wgt, int* __restrict__ slot)
{
    int t = blockIdx.x;
    int tid = threadIdx.x;
    __shared__ float sm[N_EXP][256];

    float acc[N_EXP];
#pragma unroll
    for (int e = 0; e < N_EXP; e++) acc[e] = 0.f;
#pragma unroll
    for (int j = 0; j < H_DIM / 256; j++) {
        int h = tid + j * 256;
        float xv = x[t * H_DIM + h];
#pragma unroll
        for (int e = 0; e < N_EXP; e++) acc[e] += xv * gw[e * H_DIM + h];
    }
#pragma unroll
    for (int e = 0; e < N_EXP; e++) sm[e][tid] = acc[e];
    __syncthreads();
    for (int s = 128; s > 0; s >>= 1) {
        if (tid < s) {
#pragma unroll
            for (int e = 0; e < N_EXP; e++) sm[e][tid] += sm[e][tid + s];
        }
        __syncthreads();
    }
    if (tid == 0) {
        float s[N_EXP];
#pragma unroll
        for (int e = 0; e < N_EXP; e++) {
            s[e] = sm[e][0];
            logits_out[t * N_EXP + e] = s[e];
        }
        // ---- top-1 ----
        float max1 = -INFINITY; int sel1 = 0;
        for (int e = 0; e < N_EXP; e++) if (s[e] > max1) { max1 = s[e]; sel1 = e; }
        float denom1 = 0.f;
        for (int e = 0; e < N_EXP; e++) {
            float factor = fmaxf(fabsf(s[e]), max1);
            bool m = ((max1 - s[e]) / factor) > (2.0f * JIT);
            if (!m) denom1 += expf(s[e] - max1);
        }
        float mult1 = 1.0f / denom1;  // gates1[sel1] = exp(0)/denom
        // ---- top-2 (mask out sel1) ----
        float max2 = -INFINITY; int sel2 = 0;
        for (int e = 0; e < N_EXP; e++)
            if (e != sel1 && s[e] > max2) { max2 = s[e]; sel2 = e; }
        float denom2 = 0.f;
        for (int e = 0; e < N_EXP; e++) {
            if (e == sel1) continue;
            float factor = fmaxf(fabsf(s[e]), max2);
            bool m = ((max2 - s[e]) / factor) > (2.0f * JIT);
            if (!m) denom2 += expf(s[e] - max2);
        }
        float mult2 = 1.0f / denom2;

        int p1 = atomicAdd(&cnt[sel1], 1);
        tok[sel1 * T_TOK + p1] = t; wgt[sel1 * T_TOK + p1] = mult1; slot[sel1 * T_TOK + p1] = 0;
        int p2 = atomicAdd(&cnt[sel2], 1);
        tok[sel2 * T_TOK + p2] = t; wgt[sel2 * T_TOK + p2] = mult2; slot[sel2 * T_TOK + p2] = 1;
    }
}

// ---------------- prefix sum of counts ----------------
__global__ void prefix_k(const int* __restrict__ cnt, int* __restrict__ base)
{
    if (threadIdx.x == 0 && blockIdx.x == 0) {
        int a = 0;
        for (int e = 0; e < N_EXP; e++) { base[e] = a; a += cnt[e]; }
    }
}

// ---------------- GEMM1: inter = silu(x@w1^T) * (x@w3^T), gathered rows ----------------
// grid (mtiles=16, ntiles=F/64=32, E=8), block 256 (wave w owns rows [w*16, w*16+16))
__global__ __launch_bounds__(256) void gemm1_k(
    const float* __restrict__ x,
    const float* __restrict__ w1,
    const float* __restrict__ w3,
    const int* __restrict__ cnt, const int* __restrict__ base,
    const int* __restrict__ tok,
    bf16_t* __restrict__ inter)
{
    int e = blockIdx.z;
    int cntE = cnt[e];
    int m0 = blockIdx.x * 64;
    if (m0 >= cntE) return;
    int nt = blockIdx.y;
    int tid = threadIdx.x;
    int wave = tid >> 6, lane = tid & 63, quad = lane >> 4, l16 = lane & 15;
    int mbase = m0 + wave * 16;

    int ar = mbase + l16;
    int arc = ar < cntE ? ar : cntE - 1;
    int tokA = tok[e * T_TOK + arc];
    const float* aRow = x + (size_t)tokA * H_DIM;
    const float* w1e = w1 + (size_t)e * F_DIM * H_DIM;
    const float* w3e = w3 + (size_t)e * F_DIM * H_DIM;
    int f0 = nt * 64 + l16;

    f32x4 acc1[4], acc3[4];
#pragma unroll
    for (int nb = 0; nb < 4; nb++) {
        acc1[nb] = f32x4{0.f, 0.f, 0.f, 0.f};
        acc3[nb] = f32x4{0.f, 0.f, 0.f, 0.f};
    }

    for (int ks = 0; ks < H_DIM / 32; ks++) {
        int k = ks * 32 + quad * 8;
        bf16x8 a = cvt8(aRow + k);
#pragma unroll
        for (int nb = 0; nb < 4; nb++) {
            size_t frow = (size_t)(f0 + nb * 16) * H_DIM + k;
            bf16x8 b1 = cvt8(w1e + frow);
            bf16x8 b3 = cvt8(w3e + frow);
            acc1[nb] = __builtin_amdgcn_mfma_f32_16x16x32_bf16(a, b1, acc1[nb], 0, 0, 0);
            acc3[nb] = __builtin_amdgcn_mfma_f32_16x16x32_bf16(a, b3, acc3[nb], 0, 0, 0);
        }
    }

    int rowBase = base[e];
#pragma unroll
    for (int nb = 0; nb < 4; nb++) {
        int ff = f0 + nb * 16;
#pragma unroll
        for (int r = 0; r < 4; r++) {
            int mm = mbase + quad * 4 + r;  // D row = quad*4 + reg
            if (mm < cntE) {
                float h1 = acc1[nb][r], h3 = acc3[nb][r];
                float v = (h1 / (1.f + expf(-h1))) * h3;  // silu(h1)*h3
                inter[(size_t)(rowBase + mm) * F_DIM + ff] = (bf16_t)v;
            }
        }
    }
}

// ---------------- GEMM2: out = (inter @ w2^T) * wgt, scatter to slot accumulator ----------------
// grid (mtiles=16, ntiles=H/64=16, E=8), block 256
__global__ __launch_bounds__(256) void gemm2_k(
    const bf16_t* __restrict__ inter,
    const float* __restrict__ w2,
    const int* __restrict__ cnt, const int* __restrict__ base,
    const int* __restrict__ tok,
    const float* __restrict__ wgt, const int* __restrict__ slot,
    float* __restrict__ accOut)
{
    int e = blockIdx.z;
    int cntE = cnt[e];
    int m0 = blockIdx.x * 64;
    if (m0 >= cntE) return;
    int nt = blockIdx.y;
    int tid = threadIdx.x;
    int wave = tid >> 6, lane = tid & 63, quad = lane >> 4, l16 = lane & 15;
    int mbase = m0 + wave * 16;
    int rowBase = base[e];

    int ar = mbase + l16;
    int arc = ar < cntE ? ar : cntE - 1;
    const bf16_t* aRow = inter + (size_t)(rowBase + arc) * F_DIM;
    const float* w2e = w2 + (size_t)e * H_DIM * F_DIM;
    int h0 = nt * 64 + l16;

    f32x4 acc[4];
#pragma unroll
    for (int nb = 0; nb < 4; nb++) acc[nb] = f32x4{0.f, 0.f, 0.f, 0.f};

    for (int ks = 0; ks < F_DIM / 32; ks++) {
        int k = ks * 32 + quad * 8;
        bf16x8 a = *(const bf16x8*)(aRow + k);
#pragma unroll
        for (int nb = 0; nb < 4; nb++) {
            bf16x8 b = cvt8(w2e + (size_t)(h0 + nb * 16) * F_DIM + k);
            acc[nb] = __builtin_amdgcn_mfma_f32_16x16x32_bf16(a, b, acc[nb], 0, 0, 0);
        }
    }

#pragma unroll
    for (int nb = 0; nb < 4; nb++) {
        int hh = h0 + nb * 16;
#pragma unroll
        for (int r = 0; r < 4; r++) {
            int mm = mbase + quad * 4 + r;
            if (mm < cntE) {
                int t = tok[e * T_TOK + mm];
                float wv = wgt[e * T_TOK + mm];
                int sl = slot[e * T_TOK + mm];
                accOut[(size_t)sl * T_TOK * H_DIM + (size_t)t * H_DIM + hh] = acc[nb][r] * wv;
            }
        }
    }
}

// ---------------- combine: final = acc_slot0 + acc_slot1 (f32 out) ----------------
__global__ __launch_bounds__(256) void combine_k(const float* __restrict__ acc,
                                                 float* __restrict__ out)
{
    int i = blockIdx.x * 256 + threadIdx.x;  // over (T*H)/4 float4 groups
    const float4* a0 = (const float4*)acc;
    const float4* a1 = (const float4*)(acc + (size_t)T_TOK * H_DIM);
    float4 v0 = a0[i];
    float4 v1 = a1[i];
    float4 r;
    r.x = v0.x + v1.x;
    r.y = v0.y + v1.y;
    r.z = v0.z + v1.z;
    r.w = v0.w + v1.w;
    ((float4*)out)[i] = r;
}

extern "C" void kernel_launch(void* const* d_in, const int* in_sizes, int n_in,
                              void* d_out, int out_size, void* d_ws, size_t ws_size,
                              hipStream_t stream) {
    const float* x  = (const float*)d_in[0];
    const float* gw = (const float*)d_in[1];
    const float* w1 = (const float*)d_in[2];
    const float* w2 = (const float*)d_in[3];
    const float* w3 = (const float*)d_in[4];
    float* out = (float*)d_out;
    float* logits_out = out + (size_t)T_TOK * H_DIM;

    char* ws = (char*)d_ws;
    int*    cnt   = (int*)(ws + WS_CNT);
    int*    basep = (int*)(ws + WS_BASE);
    int*    tok   = (int*)(ws + WS_TOK);
    float*  wgt   = (float*)(ws + WS_WGT);
    int*    slot  = (int*)(ws + WS_SLOT);
    bf16_t* inter = (bf16_t*)(ws + WS_INTER);
    float*  accO  = (float*)(ws + WS_ACC);

    hipMemsetAsync(cnt, 0, 64, stream);  // zero cnt
    router_k<<<T_TOK, 256, 0, stream>>>(x, gw, logits_out, cnt, tok, wgt, slot);
    prefix_k<<<1, 64, 0, stream>>>(cnt, basep);
    gemm1_k<<<dim3(16, 32, 8), 256, 0, stream>>>(x, w1, w3, cnt, basep, tok, inter);
    gemm2_k<<<dim3(16, 16, 8), 256, 0, stream>>>(inter, w2, cnt, basep, tok, wgt, slot, accO);
    combine_k<<<(T_TOK * H_DIM / 4) / 256, 256, 0, stream>>>(accO, out);
}

// Round 4
// 546.375 us; speedup vs baseline: 3.0623x; 3.0623x over previous
//
#include <hip/hip_runtime.h>
#include <hip/hip_bf16.h>
#include <math.h>

// PhiMoE sparse MoE block. E=8, H=1024, F=2048, T=1024.
// Inputs  (float32): hidden_states [1,1024,1024], gate_w [8,1024],
//   w1 [8,2048,1024], w2 [8,1024,2048], w3 [8,2048,1024]
// Outputs (float32, concat): final [1,1024,1024], router_logits [1024,8]
// Top-2 routing -> gather per expert, LDS-tiled grouped GEMMs (f32 -> bf16 cvt in staging).

#define T_TOK 1024
#define H_DIM 1024
#define F_DIM 2048
#define N_EXP 8
#define JIT 0.01f

typedef __bf16 bf16_t;
typedef __bf16 bf16x8 __attribute__((ext_vector_type(8)));
typedef __bf16 bf16x4 __attribute__((ext_vector_type(4)));
typedef float f32x4 __attribute__((ext_vector_type(4)));

#define LDP 40  // padded LDS row stride (elements) for 32-k tiles: bank-decorrelated

__device__ inline bf16x4 cvt4(float4 v) {
    bf16x4 r;
    r[0] = (bf16_t)v.x; r[1] = (bf16_t)v.y; r[2] = (bf16_t)v.z; r[3] = (bf16_t)v.w;
    return r;
}

// workspace layout (bytes)
#define WS_CNT   0
#define WS_BASE  64
#define WS_TOK   128
#define WS_WGT   (128 + 32768)
#define WS_SLOT  (WS_WGT + 32768)
#define WS_INTER 131072              // bf16 [2048][2048] compacted intermediate (8 MB)
#define WS_ACC   (131072 + 8388608)  // f32  [2][1024][1024] slot accumulators (8 MB)

// ---------------- Router: logits + sparsemixer top-2 ----------------
__global__ __launch_bounds__(256) void router_k(
    const float* __restrict__ x, const float* __restrict__ gw,
    float* __restrict__ logits_out,
    int* __restrict__ cnt, int* __restrict__ tok,
    float* __restrict__ wgt, int* __restrict__ slot)
{
    int t = blockIdx.x;
    int tid = threadIdx.x;
    __shared__ float sm[N_EXP][256];

    float acc[N_EXP];
#pragma unroll
    for (int e = 0; e < N_EXP; e++) acc[e] = 0.f;
#pragma unroll
    for (int j = 0; j < H_DIM / 256; j++) {
        int h = tid + j * 256;
        float xv = x[t * H_DIM + h];
#pragma unroll
        for (int e = 0; e < N_EXP; e++) acc[e] += xv * gw[e * H_DIM + h];
    }
#pragma unroll
    for (int e = 0; e < N_EXP; e++) sm[e][tid] = acc[e];
    __syncthreads();
    for (int s = 128; s > 0; s >>= 1) {
        if (tid < s) {
#pragma unroll
            for (int e = 0; e < N_EXP; e++) sm[e][tid] += sm[e][tid + s];
        }
        __syncthreads();
    }
    if (tid == 0) {
        float s[N_EXP];
#pragma unroll
        for (int e = 0; e < N_EXP; e++) {
            s[e] = sm[e][0];
            logits_out[t * N_EXP + e] = s[e];
        }
        float max1 = -INFINITY; int sel1 = 0;
        for (int e = 0; e < N_EXP; e++) if (s[e] > max1) { max1 = s[e]; sel1 = e; }
        float denom1 = 0.f;
        for (int e = 0; e < N_EXP; e++) {
            float factor = fmaxf(fabsf(s[e]), max1);
            bool m = ((max1 - s[e]) / factor) > (2.0f * JIT);
            if (!m) denom1 += expf(s[e] - max1);
        }
        float mult1 = 1.0f / denom1;
        float max2 = -INFINITY; int sel2 = 0;
        for (int e = 0; e < N_EXP; e++)
            if (e != sel1 && s[e] > max2) { max2 = s[e]; sel2 = e; }
        float denom2 = 0.f;
        for (int e = 0; e < N_EXP; e++) {
            if (e == sel1) continue;
            float factor = fmaxf(fabsf(s[e]), max2);
            bool m = ((max2 - s[e]) / factor) > (2.0f * JIT);
            if (!m) denom2 += expf(s[e] - max2);
        }
        float mult2 = 1.0f / denom2;

        int p1 = atomicAdd(&cnt[sel1], 1);
        tok[sel1 * T_TOK + p1] = t; wgt[sel1 * T_TOK + p1] = mult1; slot[sel1 * T_TOK + p1] = 0;
        int p2 = atomicAdd(&cnt[sel2], 1);
        tok[sel2 * T_TOK + p2] = t; wgt[sel2 * T_TOK + p2] = mult2; slot[sel2 * T_TOK + p2] = 1;
    }
}

__global__ void prefix_k(const int* __restrict__ cnt, int* __restrict__ base)
{
    if (threadIdx.x == 0 && blockIdx.x == 0) {
        int a = 0;
        for (int e = 0; e < N_EXP; e++) { base[e] = a; a += cnt[e]; }
    }
}

// ---------------- GEMM1: inter = silu(x@w1^T) * (x@w3^T) ----------------
// 128x128 tile, dual-B (w1,w3 share A tile). grid (8, 16, 8), block 256.
// Wave (wr,wc) computes rows [wr*64,+64), cols [wc*64,+64) of the tile.
__global__ __launch_bounds__(256) void gemm1_k(
    const float* __restrict__ x,
    const float* __restrict__ w1,
    const float* __restrict__ w3,
    const int* __restrict__ cnt, const int* __restrict__ base,
    const int* __restrict__ tok,
    bf16_t* __restrict__ inter)
{
    int e = blockIdx.z;
    int cntE = cnt[e];
    int m0 = blockIdx.x * 128;
    if (m0 >= cntE) return;
    int n0 = blockIdx.y * 128;
    int tid = threadIdx.x;
    int lane = tid & 63, quad = lane >> 4, l16 = lane & 15;
    int wave = tid >> 6, wr = wave >> 1, wc = wave & 1;

    __shared__ __align__(16) bf16_t Al[128 * LDP];
    __shared__ __align__(16) bf16_t B1l[128 * LDP];
    __shared__ __align__(16) bf16_t B3l[128 * LDP];
    __shared__ int tokL[128];

    if (tid < 128) {
        int r = m0 + tid;
        tokL[tid] = tok[e * T_TOK + (r < cntE ? r : cntE - 1)];
    }
    __syncthreads();

    // per-thread staging coordinates: chunk c = tid + i*256; row = c>>3, kchunk = c&7
    const float* aP[4];
    int sRow[4], sKc[4];
#pragma unroll
    for (int i = 0; i < 4; i++) {
        int c = tid + i * 256;
        sRow[i] = c >> 3; sKc[i] = c & 7;
        aP[i] = x + (size_t)tokL[sRow[i]] * H_DIM + sKc[i] * 4;
    }
    const float* w1e = w1 + (size_t)e * F_DIM * H_DIM;
    const float* w3e = w3 + (size_t)e * F_DIM * H_DIM;

    f32x4 acc1[4][4], acc3[4][4];
#pragma unroll
    for (int i = 0; i < 4; i++)
#pragma unroll
        for (int j = 0; j < 4; j++) {
            acc1[i][j] = f32x4{0.f, 0.f, 0.f, 0.f};
            acc3[i][j] = f32x4{0.f, 0.f, 0.f, 0.f};
        }

    for (int kk = 0; kk < H_DIM / 32; kk++) {
        int k0 = kk * 32;
        __syncthreads();  // previous compute done before overwriting LDS
#pragma unroll
        for (int i = 0; i < 4; i++) {
            float4 va = *(const float4*)(aP[i] + k0);
            size_t wOff = (size_t)(n0 + sRow[i]) * H_DIM + k0 + sKc[i] * 4;
            float4 v1 = *(const float4*)(w1e + wOff);
            float4 v3 = *(const float4*)(w3e + wOff);
            int ld = sRow[i] * LDP + sKc[i] * 4;
            *(bf16x4*)&Al[ld]  = cvt4(va);
            *(bf16x4*)&B1l[ld] = cvt4(v1);
            *(bf16x4*)&B3l[ld] = cvt4(v3);
        }
        __syncthreads();
        bf16x8 af[4], b1f[4], b3f[4];
#pragma unroll
        for (int i = 0; i < 4; i++)
            af[i] = *(const bf16x8*)&Al[(wr * 64 + i * 16 + l16) * LDP + quad * 8];
#pragma unroll
        for (int j = 0; j < 4; j++) {
            b1f[j] = *(const bf16x8*)&B1l[(wc * 64 + j * 16 + l16) * LDP + quad * 8];
            b3f[j] = *(const bf16x8*)&B3l[(wc * 64 + j * 16 + l16) * LDP + quad * 8];
        }
#pragma unroll
        for (int i = 0; i < 4; i++)
#pragma unroll
            for (int j = 0; j < 4; j++) {
                acc1[i][j] = __builtin_amdgcn_mfma_f32_16x16x32_bf16(af[i], b1f[j], acc1[i][j], 0, 0, 0);
                acc3[i][j] = __builtin_amdgcn_mfma_f32_16x16x32_bf16(af[i], b3f[j], acc3[i][j], 0, 0, 0);
            }
    }

    int rowBase = base[e];
#pragma unroll
    for (int i = 0; i < 4; i++) {
#pragma unroll
        for (int j = 0; j < 4; j++) {
            int ff = n0 + wc * 64 + j * 16 + l16;
#pragma unroll
            for (int r = 0; r < 4; r++) {
                int mm = m0 + wr * 64 + i * 16 + quad * 4 + r;
                if (mm < cntE) {
                    float h1 = acc1[i][j][r], h3 = acc3[i][j][r];
                    float v = (h1 / (1.f + expf(-h1))) * h3;
                    inter[(size_t)(rowBase + mm) * F_DIM + ff] = (bf16_t)v;
                }
            }
        }
    }
}

// ---------------- GEMM2: out = (inter @ w2^T) * wgt, scatter to slot accumulator ----------------
// 64x128 tile. grid (16, 8, 8), block 256. Wave (wr,wc): rows [wr*32,+32), cols [wc*64,+64).
__global__ __launch_bounds__(256) void gemm2_k(
    const bf16_t* __restrict__ inter,
    const float* __restrict__ w2,
    const int* __restrict__ cnt, const int* __restrict__ base,
    const int* __restrict__ tok,
    const float* __restrict__ wgt, const int* __restrict__ slot,
    float* __restrict__ accOut)
{
    int e = blockIdx.z;
    int cntE = cnt[e];
    int m0 = blockIdx.x * 64;
    if (m0 >= cntE) return;
    int n0 = blockIdx.y * 128;
    int tid = threadIdx.x;
    int lane = tid & 63, quad = lane >> 4, l16 = lane & 15;
    int wave = tid >> 6, wr = wave >> 1, wc = wave & 1;
    int rowBase = base[e];

    __shared__ __align__(16) bf16_t Al[64 * LDP];
    __shared__ __align__(16) bf16_t Bl[128 * LDP];

    // A staging: 64 rows x 32 k bf16 = 256 x (8-elem chunks); thread -> r=tid>>2, kc=tid&3
    int aR = tid >> 2, aKc = tid & 3;
    int aRow = m0 + aR; if (aRow >= cntE) aRow = cntE - 1;
    const bf16_t* aP = inter + (size_t)(rowBase + aRow) * F_DIM + aKc * 8;
    // B staging: 128 rows x 32 k f32: chunk c = tid + i*256; r=c>>3, kc=c&7
    const float* w2e = w2 + (size_t)e * H_DIM * F_DIM;

    f32x4 acc[2][4];
#pragma unroll
    for (int i = 0; i < 2; i++)
#pragma unroll
        for (int j = 0; j < 4; j++) acc[i][j] = f32x4{0.f, 0.f, 0.f, 0.f};

    for (int kk = 0; kk < F_DIM / 32; kk++) {
        int k0 = kk * 32;
        __syncthreads();
        *(bf16x8*)&Al[aR * LDP + aKc * 8] = *(const bf16x8*)(aP + k0);
#pragma unroll
        for (int i = 0; i < 4; i++) {
            int c = tid + i * 256;
            int r = c >> 3, kc = c & 7;
            float4 v = *(const float4*)(w2e + (size_t)(n0 + r) * F_DIM + k0 + kc * 4);
            *(bf16x4*)&Bl[r * LDP + kc * 4] = cvt4(v);
        }
        __syncthreads();
        bf16x8 af[2], bfr[4];
#pragma unroll
        for (int i = 0; i < 2; i++)
            af[i] = *(const bf16x8*)&Al[(wr * 32 + i * 16 + l16) * LDP + quad * 8];
#pragma unroll
        for (int j = 0; j < 4; j++)
            bfr[j] = *(const bf16x8*)&Bl[(wc * 64 + j * 16 + l16) * LDP + quad * 8];
#pragma unroll
        for (int i = 0; i < 2; i++)
#pragma unroll
            for (int j = 0; j < 4; j++)
                acc[i][j] = __builtin_amdgcn_mfma_f32_16x16x32_bf16(af[i], bfr[j], acc[i][j], 0, 0, 0);
    }

#pragma unroll
    for (int i = 0; i < 2; i++) {
#pragma unroll
        for (int r = 0; r < 4; r++) {
            int mm = m0 + wr * 32 + i * 16 + quad * 4 + r;
            if (mm < cntE) {
                int t = tok[e * T_TOK + mm];
                float wv = wgt[e * T_TOK + mm];
                int sl = slot[e * T_TOK + mm];
                float* dst = accOut + (size_t)sl * T_TOK * H_DIM + (size_t)t * H_DIM;
#pragma unroll
                for (int j = 0; j < 4; j++)
                    dst[n0 + wc * 64 + j * 16 + l16] = acc[i][j][r] * wv;
            }
        }
    }
}

// ---------------- combine ----------------
__global__ __launch_bounds__(256) void combine_k(const float* __restrict__ acc,
                                                 float* __restrict__ out)
{
    int i = blockIdx.x * 256 + threadIdx.x;
    const float4* a0 = (const float4*)acc;
    const float4* a1 = (const float4*)(acc + (size_t)T_TOK * H_DIM);
    float4 v0 = a0[i];
    float4 v1 = a1[i];
    float4 r;
    r.x = v0.x + v1.x; r.y = v0.y + v1.y; r.z = v0.z + v1.z; r.w = v0.w + v1.w;
    ((float4*)out)[i] = r;
}

extern "C" void kernel_launch(void* const* d_in, const int* in_sizes, int n_in,
                              void* d_out, int out_size, void* d_ws, size_t ws_size,
                              hipStream_t stream) {
    const float* x  = (const float*)d_in[0];
    const float* gw = (const float*)d_in[1];
    const float* w1 = (const float*)d_in[2];
    const float* w2 = (const float*)d_in[3];
    const float* w3 = (const float*)d_in[4];
    float* out = (float*)d_out;
    float* logits_out = out + (size_t)T_TOK * H_DIM;

    char* ws = (char*)d_ws;
    int*    cnt   = (int*)(ws + WS_CNT);
    int*    basep = (int*)(ws + WS_BASE);
    int*    tok   = (int*)(ws + WS_TOK);
    float*  wgt   = (float*)(ws + WS_WGT);
    int*    slot  = (int*)(ws + WS_SLOT);
    bf16_t* inter = (bf16_t*)(ws + WS_INTER);
    float*  accO  = (float*)(ws + WS_ACC);

    hipMemsetAsync(cnt, 0, 64, stream);
    router_k<<<T_TOK, 256, 0, stream>>>(x, gw, logits_out, cnt, tok, wgt, slot);
    prefix_k<<<1, 64, 0, stream>>>(cnt, basep);
    gemm1_k<<<dim3(8, 16, 8), 256, 0, stream>>>(x, w1, w3, cnt, basep, tok, inter);
    gemm2_k<<<dim3(16, 8, 8), 256, 0, stream>>>(inter, w2, cnt, basep, tok, wgt, slot, accO);
    combine_k<<<(T_TOK * H_DIM / 4) / 256, 256, 0, stream>>>(accO, out);
}

// Round 5
// 471.291 us; speedup vs baseline: 3.5502x; 1.1593x over previous
//
#include <hip/hip_runtime.h>
#include <hip/hip_bf16.h>
#include <math.h>

// PhiMoE sparse MoE block. E=8, H=1024, F=2048, T=1024.
// Inputs  (float32): hidden_states [1,1024,1024], gate_w [8,1024],
//   w1 [8,2048,1024], w2 [8,1024,2048], w3 [8,2048,1024]
// Outputs (float32, concat): final [1,1024,1024], router_logits [1024,8]
// Top-2 routing -> gather per expert; pipelined LDS-dbuf grouped GEMMs
// (reg-prefetch depth 1, one barrier per K-iter, f32->bf16 cvt in staging).

#define T_TOK 1024
#define H_DIM 1024
#define F_DIM 2048
#define N_EXP 8
#define JIT 0.01f

#define BK  64
#define LDK 72   // LDS row stride (bf16 elems): conflict-free for b64 writes + b128 reads

typedef __bf16 bf16_t;
typedef __bf16 bf16x8 __attribute__((ext_vector_type(8)));
typedef __bf16 bf16x4 __attribute__((ext_vector_type(4)));
typedef float f32x4 __attribute__((ext_vector_type(4)));

__device__ inline bf16x4 cvt4(float4 v) {
    bf16x4 r;
    r[0] = (bf16_t)v.x; r[1] = (bf16_t)v.y; r[2] = (bf16_t)v.z; r[3] = (bf16_t)v.w;
    return r;
}

// workspace layout (bytes)
#define WS_CNT   0
#define WS_BASE  64
#define WS_TOK   128
#define WS_WGT   (128 + 32768)
#define WS_SLOT  (WS_WGT + 32768)
#define WS_INTER 131072              // bf16 [2048][2048] compacted intermediate (8 MB)
#define WS_ACC   (131072 + 8388608)  // f32  [2][1024][1024] slot accumulators (8 MB)

// ---------------- Router: logits + sparsemixer top-2 ----------------
__global__ __launch_bounds__(256) void router_k(
    const float* __restrict__ x, const float* __restrict__ gw,
    float* __restrict__ logits_out,
    int* __restrict__ cnt, int* __restrict__ tok,
    float* __restrict__ wgt, int* __restrict__ slot)
{
    int t = blockIdx.x;
    int tid = threadIdx.x;
    __shared__ float sm[N_EXP][256];

    float acc[N_EXP];
#pragma unroll
    for (int e = 0; e < N_EXP; e++) acc[e] = 0.f;
#pragma unroll
    for (int j = 0; j < H_DIM / 256; j++) {
        int h = tid + j * 256;
        float xv = x[t * H_DIM + h];
#pragma unroll
        for (int e = 0; e < N_EXP; e++) acc[e] += xv * gw[e * H_DIM + h];
    }
#pragma unroll
    for (int e = 0; e < N_EXP; e++) sm[e][tid] = acc[e];
    __syncthreads();
    for (int s = 128; s > 0; s >>= 1) {
        if (tid < s) {
#pragma unroll
            for (int e = 0; e < N_EXP; e++) sm[e][tid] += sm[e][tid + s];
        }
        __syncthreads();
    }
    if (tid == 0) {
        float s[N_EXP];
#pragma unroll
        for (int e = 0; e < N_EXP; e++) {
            s[e] = sm[e][0];
            logits_out[t * N_EXP + e] = s[e];
        }
        float max1 = -INFINITY; int sel1 = 0;
        for (int e = 0; e < N_EXP; e++) if (s[e] > max1) { max1 = s[e]; sel1 = e; }
        float denom1 = 0.f;
        for (int e = 0; e < N_EXP; e++) {
            float factor = fmaxf(fabsf(s[e]), max1);
            bool m = ((max1 - s[e]) / factor) > (2.0f * JIT);
            if (!m) denom1 += expf(s[e] - max1);
        }
        float mult1 = 1.0f / denom1;
        float max2 = -INFINITY; int sel2 = 0;
        for (int e = 0; e < N_EXP; e++)
            if (e != sel1 && s[e] > max2) { max2 = s[e]; sel2 = e; }
        float denom2 = 0.f;
        for (int e = 0; e < N_EXP; e++) {
            if (e == sel1) continue;
            float factor = fmaxf(fabsf(s[e]), max2);
            bool m = ((max2 - s[e]) / factor) > (2.0f * JIT);
            if (!m) denom2 += expf(s[e] - max2);
        }
        float mult2 = 1.0f / denom2;

        int p1 = atomicAdd(&cnt[sel1], 1);
        tok[sel1 * T_TOK + p1] = t; wgt[sel1 * T_TOK + p1] = mult1; slot[sel1 * T_TOK + p1] = 0;
        int p2 = atomicAdd(&cnt[sel2], 1);
        tok[sel2 * T_TOK + p2] = t; wgt[sel2 * T_TOK + p2] = mult2; slot[sel2 * T_TOK + p2] = 1;
    }
}

__global__ void prefix_k(const int* __restrict__ cnt, int* __restrict__ base)
{
    if (threadIdx.x == 0 && blockIdx.x == 0) {
        int a = 0;
        for (int e = 0; e < N_EXP; e++) { base[e] = a; a += cnt[e]; }
    }
}

// ---------------- GEMM1: inter = silu(x@w1^T) * (x@w3^T) ----------------
// 128x64 tile, BK=64, LDS double-buffer + reg prefetch, one barrier per iter.
// grid (8, 32, 8), block 256. Wave w: rows [32w,+32), all 64 cols, both mats.
__global__ __launch_bounds__(256) void gemm1_k(
    const float* __restrict__ x,
    const float* __restrict__ w1,
    const float* __restrict__ w3,
    const int* __restrict__ cnt, const int* __restrict__ base,
    const int* __restrict__ tok,
    bf16_t* __restrict__ inter)
{
    int e = blockIdx.z;
    int cntE = cnt[e];
    int m0 = blockIdx.x * 128;
    if (m0 >= cntE) return;
    int n0 = blockIdx.y * 64;
    int tid = threadIdx.x;
    int lane = tid & 63, quad = lane >> 4, l16 = lane & 15;
    int wave = tid >> 6;

    __shared__ __align__(16) bf16_t Al[2][128 * LDK];
    __shared__ __align__(16) bf16_t B1l[2][64 * LDK];
    __shared__ __align__(16) bf16_t B3l[2][64 * LDK];
    __shared__ int tokL[128];

    if (tid < 128) {
        int r = m0 + tid;
        tokL[tid] = tok[e * T_TOK + (r < cntE ? r : cntE - 1)];
    }
    __syncthreads();

    // staging coords: A 128x64 f32 = 2048 float4 chunks (8/thread); B 64x64 = 1024 (4/thread)
    int rA[8], kA[8];
    const float* aP[8];
#pragma unroll
    for (int i = 0; i < 8; i++) {
        int c = tid + i * 256;
        rA[i] = c >> 4; kA[i] = c & 15;
        aP[i] = x + (size_t)tokL[rA[i]] * H_DIM + kA[i] * 4;
    }
    int rB[4], kB[4];
    const float* b1P[4];
    const float* b3P[4];
    const float* w1e = w1 + (size_t)e * F_DIM * H_DIM + (size_t)n0 * H_DIM;
    const float* w3e = w3 + (size_t)e * F_DIM * H_DIM + (size_t)n0 * H_DIM;
#pragma unroll
    for (int i = 0; i < 4; i++) {
        int c = tid + i * 256;
        rB[i] = c >> 4; kB[i] = c & 15;
        b1P[i] = w1e + (size_t)rB[i] * H_DIM + kB[i] * 4;
        b3P[i] = w3e + (size_t)rB[i] * H_DIM + kB[i] * 4;
    }

    f32x4 acc1[2][4], acc3[2][4];
#pragma unroll
    for (int i = 0; i < 2; i++)
#pragma unroll
        for (int j = 0; j < 4; j++) {
            acc1[i][j] = f32x4{0.f, 0.f, 0.f, 0.f};
            acc3[i][j] = f32x4{0.f, 0.f, 0.f, 0.f};
        }

    float4 pA[8], p1[4], p3[4];
#pragma unroll
    for (int i = 0; i < 8; i++) pA[i] = *(const float4*)(aP[i]);
#pragma unroll
    for (int i = 0; i < 4; i++) { p1[i] = *(const float4*)(b1P[i]); p3[i] = *(const float4*)(b3P[i]); }

    for (int kk = 0; kk < H_DIM / BK; kk++) {
        int buf = kk & 1;
        // stage prefetched regs into LDS (vmcnt wait lands here, one iter after issue)
#pragma unroll
        for (int i = 0; i < 8; i++)
            *(bf16x4*)&Al[buf][rA[i] * LDK + kA[i] * 4] = cvt4(pA[i]);
#pragma unroll
        for (int i = 0; i < 4; i++) {
            *(bf16x4*)&B1l[buf][rB[i] * LDK + kB[i] * 4] = cvt4(p1[i]);
            *(bf16x4*)&B3l[buf][rB[i] * LDK + kB[i] * 4] = cvt4(p3[i]);
        }
        // issue next iter's loads (overlap with MFMA phase below)
        if (kk + 1 < H_DIM / BK) {
            int k0 = (kk + 1) * BK;
#pragma unroll
            for (int i = 0; i < 8; i++) pA[i] = *(const float4*)(aP[i] + k0);
#pragma unroll
            for (int i = 0; i < 4; i++) {
                p1[i] = *(const float4*)(b1P[i] + k0);
                p3[i] = *(const float4*)(b3P[i] + k0);
            }
        }
        __syncthreads();
#pragma unroll
        for (int s = 0; s < 2; s++) {
            int ko = s * 32 + quad * 8;
            bf16x8 af[2], b1f[4], b3f[4];
#pragma unroll
            for (int i = 0; i < 2; i++)
                af[i] = *(const bf16x8*)&Al[buf][(wave * 32 + i * 16 + l16) * LDK + ko];
#pragma unroll
            for (int j = 0; j < 4; j++) {
                b1f[j] = *(const bf16x8*)&B1l[buf][(j * 16 + l16) * LDK + ko];
                b3f[j] = *(const bf16x8*)&B3l[buf][(j * 16 + l16) * LDK + ko];
            }
#pragma unroll
            for (int i = 0; i < 2; i++)
#pragma unroll
                for (int j = 0; j < 4; j++) {
                    acc1[i][j] = __builtin_amdgcn_mfma_f32_16x16x32_bf16(af[i], b1f[j], acc1[i][j], 0, 0, 0);
                    acc3[i][j] = __builtin_amdgcn_mfma_f32_16x16x32_bf16(af[i], b3f[j], acc3[i][j], 0, 0, 0);
                }
        }
    }

    int rowBase = base[e];
#pragma unroll
    for (int i = 0; i < 2; i++) {
#pragma unroll
        for (int j = 0; j < 4; j++) {
            int ff = n0 + j * 16 + l16;
#pragma unroll
            for (int r = 0; r < 4; r++) {
                int mm = m0 + wave * 32 + i * 16 + quad * 4 + r;
                if (mm < cntE) {
                    float h1 = acc1[i][j][r], h3 = acc3[i][j][r];
                    float v = (h1 / (1.f + expf(-h1))) * h3;
                    inter[(size_t)(rowBase + mm) * F_DIM + ff] = (bf16_t)v;
                }
            }
        }
    }
}

// ---------------- GEMM2: out = (inter @ w2^T) * wgt, scatter to slot accumulator ----------------
// 64x64 tile, BK=64, same pipeline. grid (16, 16, 8), block 256. Wave w: rows [16w,+16).
__global__ __launch_bounds__(256) void gemm2_k(
    const bf16_t* __restrict__ inter,
    const float* __restrict__ w2,
    const int* __restrict__ cnt, const int* __restrict__ base,
    const int* __restrict__ tok,
    const float* __restrict__ wgt, const int* __restrict__ slot,
    float* __restrict__ accOut)
{
    int e = blockIdx.z;
    int cntE = cnt[e];
    int m0 = blockIdx.x * 64;
    if (m0 >= cntE) return;
    int n0 = blockIdx.y * 64;
    int tid = threadIdx.x;
    int lane = tid & 63, quad = lane >> 4, l16 = lane & 15;
    int wave = tid >> 6;
    int rowBase = base[e];

    __shared__ __align__(16) bf16_t Al[2][64 * LDK];
    __shared__ __align__(16) bf16_t Bl[2][64 * LDK];

    // A: 64x64 bf16 = 512 bf16x8 chunks (2/thread); B: 64x64 f32 = 1024 float4 (4/thread)
    int rA[2], kA[2];
    const bf16_t* aP[2];
#pragma unroll
    for (int i = 0; i < 2; i++) {
        int c = tid + i * 256;
        rA[i] = c >> 3; kA[i] = c & 7;
        int row = m0 + rA[i]; if (row >= cntE) row = cntE - 1;
        aP[i] = inter + (size_t)(rowBase + row) * F_DIM + kA[i] * 8;
    }
    int rB[4], kB[4];
    const float* bP[4];
    const float* w2e = w2 + (size_t)e * H_DIM * F_DIM + (size_t)n0 * F_DIM;
#pragma unroll
    for (int i = 0; i < 4; i++) {
        int c = tid + i * 256;
        rB[i] = c >> 4; kB[i] = c & 15;
        bP[i] = w2e + (size_t)rB[i] * F_DIM + kB[i] * 4;
    }

    f32x4 acc[4];
#pragma unroll
    for (int j = 0; j < 4; j++) acc[j] = f32x4{0.f, 0.f, 0.f, 0.f};

    bf16x8 pa[2];
    float4 pb[4];
#pragma unroll
    for (int i = 0; i < 2; i++) pa[i] = *(const bf16x8*)(aP[i]);
#pragma unroll
    for (int i = 0; i < 4; i++) pb[i] = *(const float4*)(bP[i]);

    for (int kk = 0; kk < F_DIM / BK; kk++) {
        int buf = kk & 1;
#pragma unroll
        for (int i = 0; i < 2; i++)
            *(bf16x8*)&Al[buf][rA[i] * LDK + kA[i] * 8] = pa[i];
#pragma unroll
        for (int i = 0; i < 4; i++)
            *(bf16x4*)&Bl[buf][rB[i] * LDK + kB[i] * 4] = cvt4(pb[i]);
        if (kk + 1 < F_DIM / BK) {
            int k0 = (kk + 1) * BK;
#pragma unroll
            for (int i = 0; i < 2; i++) pa[i] = *(const bf16x8*)(aP[i] + k0);
#pragma unroll
            for (int i = 0; i < 4; i++) pb[i] = *(const float4*)(bP[i] + k0);
        }
        __syncthreads();
#pragma unroll
        for (int s = 0; s < 2; s++) {
            int ko = s * 32 + quad * 8;
            bf16x8 af = *(const bf16x8*)&Al[buf][(wave * 16 + l16) * LDK + ko];
            bf16x8 bfr[4];
#pragma unroll
            for (int j = 0; j < 4; j++)
                bfr[j] = *(const bf16x8*)&Bl[buf][(j * 16 + l16) * LDK + ko];
#pragma unroll
            for (int j = 0; j < 4; j++)
                acc[j] = __builtin_amdgcn_mfma_f32_16x16x32_bf16(af, bfr[j], acc[j], 0, 0, 0);
        }
    }

#pragma unroll
    for (int r = 0; r < 4; r++) {
        int mm = m0 + wave * 16 + quad * 4 + r;
        if (mm < cntE) {
            int t = tok[e * T_TOK + mm];
            float wv = wgt[e * T_TOK + mm];
            int sl = slot[e * T_TOK + mm];
            float* dst = accOut + (size_t)sl * T_TOK * H_DIM + (size_t)t * H_DIM;
#pragma unroll
            for (int j = 0; j < 4; j++)
                dst[n0 + j * 16 + l16] = acc[j][r] * wv;
        }
    }
}

// ---------------- combine ----------------
__global__ __launch_bounds__(256) void combine_k(const float* __restrict__ acc,
                                                 float* __restrict__ out)
{
    int i = blockIdx.x * 256 + threadIdx.x;
    const float4* a0 = (const float4*)acc;
    const float4* a1 = (const float4*)(acc + (size_t)T_TOK * H_DIM);
    float4 v0 = a0[i];
    float4 v1 = a1[i];
    float4 r;
    r.x = v0.x + v1.x; r.y = v0.y + v1.y; r.z = v0.z + v1.z; r.w = v0.w + v1.w;
    ((float4*)out)[i] = r;
}

extern "C" void kernel_launch(void* const* d_in, const int* in_sizes, int n_in,
                              void* d_out, int out_size, void* d_ws, size_t ws_size,
                              hipStream_t stream) {
    const float* x  = (const float*)d_in[0];
    const float* gw = (const float*)d_in[1];
    const float* w1 = (const float*)d_in[2];
    const float* w2 = (const float*)d_in[3];
    const float* w3 = (const float*)d_in[4];
    float* out = (float*)d_out;
    float* logits_out = out + (size_t)T_TOK * H_DIM;

    char* ws = (char*)d_ws;
    int*    cnt   = (int*)(ws + WS_CNT);
    int*    basep = (int*)(ws + WS_BASE);
    int*    tok   = (int*)(ws + WS_TOK);
    float*  wgt   = (float*)(ws + WS_WGT);
    int*    slot  = (int*)(ws + WS_SLOT);
    bf16_t* inter = (bf16_t*)(ws + WS_INTER);
    float*  accO  = (float*)(ws + WS_ACC);

    hipMemsetAsync(cnt, 0, 64, stream);
    router_k<<<T_TOK, 256, 0, stream>>>(x, gw, logits_out, cnt, tok, wgt, slot);
    prefix_k<<<1, 64, 0, stream>>>(cnt, basep);
    gemm1_k<<<dim3(8, 32, 8), 256, 0, stream>>>(x, w1, w3, cnt, basep, tok, inter);
    gemm2_k<<<dim3(16, 16, 8), 256, 0, stream>>>(inter, w2, cnt, basep, tok, wgt, slot, accO);
    combine_k<<<(T_TOK * H_DIM / 4) / 256, 256, 0, stream>>>(accO, out);
}